// Round 1
// baseline (100.889 us; speedup 1.0000x reference)
//
#include <hip/hip_runtime.h>
#include <hip/hip_bf16.h>
#include <stdint.h>

#define BB   8
#define CIN  256
#define COUT 128
#define NN   4096

using f32x4  = __attribute__((ext_vector_type(4))) float;
using bf16x8 = __attribute__((ext_vector_type(8))) __bf16;
using u16x8  = __attribute__((ext_vector_type(8))) unsigned short;

static __device__ __forceinline__ unsigned short f2bf(float f) {
    unsigned int u = __builtin_bit_cast(unsigned int, f);
    u += 0x7FFFu + ((u >> 16) & 1u);
    return (unsigned short)(u >> 16);
}
static __device__ __forceinline__ bf16x8 pack8(float4 a, float4 b) {
    u16x8 r;
    r[0]=f2bf(a.x); r[1]=f2bf(a.y); r[2]=f2bf(a.z); r[3]=f2bf(a.w);
    r[4]=f2bf(b.x); r[5]=f2bf(b.y); r[6]=f2bf(b.z); r[7]=f2bf(b.w);
    return __builtin_bit_cast(bf16x8, r);
}
#define MFMA(a,b,c) __builtin_amdgcn_mfma_f32_16x16x32_bf16((a),(b),(c),0,0,0)

// swizzled LDS index (ushort units): xor byte-bit4..6 with row&7 -> conflict-free b128 reads
static __device__ __forceinline__ int sw64(int r, int c)  { return (r*64  + c) ^ ((r&7)<<3); }
static __device__ __forceinline__ int sw128(int r, int c) { return (r*128 + c) ^ ((r&7)<<3); }

// ---------------- K1: G/T/P = conv1x1(x) for g,theta,phi -> bf16 [B][128][N] ----
__global__ __launch_bounds__(256) void k1_conv3(
    const float* __restrict__ x,
    const float* __restrict__ gw, const float* __restrict__ gb,
    const float* __restrict__ tw, const float* __restrict__ tb,
    const float* __restrict__ pw, const float* __restrict__ pb,
    unsigned short* __restrict__ G, unsigned short* __restrict__ T,
    unsigned short* __restrict__ P)
{
    __shared__ __align__(16) unsigned short As[128*64];
    __shared__ __align__(16) unsigned short Bs[128*64];
    int bid = blockIdx.x;
    int b   = bid / 96;
    int r96 = bid % 96;
    int tm  = r96 >> 5;            // 0=g 1=theta 2=phi
    int n0  = (r96 & 31) * 128;
    const float* W    = (tm==0) ? gw : (tm==1) ? tw : pw;
    const float* bias = (tm==0) ? gb : (tm==1) ? tb : pb;
    unsigned short* O = (tm==0) ? G  : (tm==1) ? T  : P;

    int t = threadIdx.x;
    int lane = t & 63, wv = t >> 6;
    int wr = wv >> 1, wc = wv & 1;
    int lr = lane & 15, lg = lane >> 4;

    f32x4 acc[4][4];
    #pragma unroll
    for (int i=0;i<4;i++)
        #pragma unroll
        for (int j=0;j<4;j++) acc[i][j] = (f32x4){0.f,0.f,0.f,0.f};

    const float* xb = x + (size_t)b * CIN * NN;

    for (int kc = 0; kc < 4; ++kc) {
        int k0 = kc * 64;
        { // stage A: weight tile [128 rows][64 k] fp32 -> bf16 swizzled
            int rsub = t >> 4;
            int kq   = (t & 15) * 4;
            #pragma unroll
            for (int rr = 0; rr < 8; ++rr) {
                int row = rr*16 + rsub;
                float4 f = *(const float4*)(W + row*256 + k0 + kq);
                ushort4 pk; pk.x=f2bf(f.x); pk.y=f2bf(f.y); pk.z=f2bf(f.z); pk.w=f2bf(f.w);
                *(ushort4*)&As[sw64(row, kq)] = pk;
            }
        }
        { // stage B: x tile [64 k][128 n] -> Bs[n][k] (transposed, pair-packed)
            int nn_  = t & 127;
            int half = t >> 7;
            #pragma unroll
            for (int kk = 0; kk < 16; ++kk) {
                int p  = kk*2 + half;          // pair index 0..31
                int kg = k0 + p*2;
                float f0 = xb[(size_t)kg*NN     + n0 + nn_];
                float f1 = xb[(size_t)(kg+1)*NN + n0 + nn_];
                unsigned int pk = (unsigned int)f2bf(f0) | ((unsigned int)f2bf(f1) << 16);
                *(unsigned int*)&Bs[sw64(nn_, p*2)] = pk;
            }
        }
        __syncthreads();
        #pragma unroll
        for (int kk = 0; kk < 2; ++kk) {
            bf16x8 af[4], bfr[4];
            #pragma unroll
            for (int mi=0; mi<4; ++mi) {
                int row = wr*64 + mi*16 + lr;
                af[mi] = __builtin_bit_cast(bf16x8, *(const u16x8*)&As[sw64(row, kk*32 + lg*8)]);
            }
            #pragma unroll
            for (int ni=0; ni<4; ++ni) {
                int row = wc*64 + ni*16 + lr;
                bfr[ni] = __builtin_bit_cast(bf16x8, *(const u16x8*)&Bs[sw64(row, kk*32 + lg*8)]);
            }
            #pragma unroll
            for (int mi=0; mi<4; ++mi)
                #pragma unroll
                for (int ni=0; ni<4; ++ni)
                    acc[mi][ni] = MFMA(af[mi], bfr[ni], acc[mi][ni]);
        }
        __syncthreads();
    }
    #pragma unroll
    for (int mi=0; mi<4; ++mi) {
        #pragma unroll
        for (int j=0; j<4; ++j) {
            int c = wr*64 + mi*16 + lg*4 + j;
            float bv = bias[c];
            #pragma unroll
            for (int ni=0; ni<4; ++ni) {
                int n = n0 + wc*64 + ni*16 + lr;
                O[(size_t)b*COUT*NN + (size_t)c*NN + n] = f2bf(acc[mi][ni][j] + bv);
            }
        }
    }
}

// ---------------- K2: M1[b,k,c] = sum_n P[b,k,n]*G[b,c,n]  (K-split + atomics) ----
__global__ __launch_bounds__(256) void k2_m1(
    const unsigned short* __restrict__ P, const unsigned short* __restrict__ G,
    float* __restrict__ M1)
{
    __shared__ __align__(16) unsigned short Ps[128*64];
    __shared__ __align__(16) unsigned short Gs[128*64];
    int b  = blockIdx.x >> 4;
    int ks = blockIdx.x & 15;
    int t = threadIdx.x;
    int lane = t & 63, wv = t >> 6;
    int wr = wv >> 1, wc = wv & 1;
    int lr = lane & 15, lg = lane >> 4;

    f32x4 acc[4][4];
    #pragma unroll
    for (int i=0;i<4;i++)
        #pragma unroll
        for (int j=0;j<4;j++) acc[i][j] = (f32x4){0.f,0.f,0.f,0.f};

    const unsigned short* Pb = P + (size_t)b*COUT*NN;
    const unsigned short* Gb = G + (size_t)b*COUT*NN;

    for (int it = 0; it < 4; ++it) {
        int n0 = ks*256 + it*64;
        #pragma unroll
        for (int ss = 0; ss < 4; ++ss) {
            int idx = ss*256 + t;
            int row = idx >> 3;
            int c8  = (idx & 7) * 8;
            u16x8 v = *(const u16x8*)(Pb + (size_t)row*NN + n0 + c8);
            *(u16x8*)&Ps[sw64(row, c8)] = v;
            u16x8 g = *(const u16x8*)(Gb + (size_t)row*NN + n0 + c8);
            *(u16x8*)&Gs[sw64(row, c8)] = g;
        }
        __syncthreads();
        #pragma unroll
        for (int kk = 0; kk < 2; ++kk) {
            bf16x8 af[4], bfr[4];
            #pragma unroll
            for (int mi=0; mi<4; ++mi) {
                int row = wr*64 + mi*16 + lr;
                af[mi] = __builtin_bit_cast(bf16x8, *(const u16x8*)&Ps[sw64(row, kk*32 + lg*8)]);
            }
            #pragma unroll
            for (int ni=0; ni<4; ++ni) {
                int row = wc*64 + ni*16 + lr;
                bfr[ni] = __builtin_bit_cast(bf16x8, *(const u16x8*)&Gs[sw64(row, kk*32 + lg*8)]);
            }
            #pragma unroll
            for (int mi=0; mi<4; ++mi)
                #pragma unroll
                for (int ni=0; ni<4; ++ni)
                    acc[mi][ni] = MFMA(af[mi], bfr[ni], acc[mi][ni]);
        }
        __syncthreads();
    }
    float* m1b = M1 + (size_t)b*16384;
    #pragma unroll
    for (int mi=0; mi<4; ++mi)
        #pragma unroll
        for (int j=0; j<4; ++j) {
            int kch = wr*64 + mi*16 + lg*4 + j;
            #pragma unroll
            for (int ni=0; ni<4; ++ni) {
                int cch = wc*64 + ni*16 + lr;
                atomicAdd(&m1b[kch*128 + cch], acc[mi][ni][j]);
            }
        }
}

// ---------------- K3: W2[b,o,k] = (1/N) * sum_c Ww[o,c] * M1[b,k,c] -> bf16 ----
__global__ __launch_bounds__(256) void k3_w2(
    const float* __restrict__ Ww, const float* __restrict__ M1,
    unsigned short* __restrict__ W2)
{
    int b = blockIdx.x >> 2, q = blockIdx.x & 3;
    int wv = threadIdx.x >> 6, lane = threadIdx.x & 63;
    int lr = lane & 15, lg = lane >> 4;
    int o16 = q*64 + wv*16;

    bf16x8 a[4];
    const float* wrow = Ww + (size_t)(o16 + lr)*128;
    #pragma unroll
    for (int ksx=0; ksx<4; ++ksx) {
        float4 f0 = *(const float4*)(wrow + ksx*32 + lg*8);
        float4 f1 = *(const float4*)(wrow + ksx*32 + lg*8 + 4);
        a[ksx] = pack8(f0, f1);
    }
    const float* m1b = M1 + (size_t)b*16384;
    for (int kt = 0; kt < 8; ++kt) {
        f32x4 acc = (f32x4){0.f,0.f,0.f,0.f};
        const float* mrow = m1b + (size_t)(kt*16 + lr)*128;
        #pragma unroll
        for (int ksx=0; ksx<4; ++ksx) {
            float4 f0 = *(const float4*)(mrow + ksx*32 + lg*8);
            float4 f1 = *(const float4*)(mrow + ksx*32 + lg*8 + 4);
            bf16x8 bb = pack8(f0, f1);
            acc = MFMA(a[ksx], bb, acc);
        }
        #pragma unroll
        for (int j=0;j<4;++j) {
            int o = o16 + lg*4 + j;
            int k = kt*16 + lr;
            W2[(size_t)b*32768 + (size_t)o*128 + k] = f2bf(acc[j] * (1.0f/4096.0f));
        }
    }
}

// ---------------- K4: w_y[b] = W2[b] @ T[b] + Wb -> fp32 d_out ----
__global__ __launch_bounds__(256) void k4_wy(
    const unsigned short* __restrict__ W2, const unsigned short* __restrict__ T,
    const float* __restrict__ Wb, float* __restrict__ out)
{
    __shared__ __align__(16) unsigned short As[128*128];
    __shared__ __align__(16) unsigned short Bs[128*128];
    int bid = blockIdx.x;
    int b   = bid >> 6;
    int r64 = bid & 63;
    int o0  = (r64 >> 5) * 128;
    int n0  = (r64 & 31) * 128;
    int t = threadIdx.x;
    int lane = t & 63, wv = t >> 6;
    int wr = wv >> 1, wc = wv & 1;
    int lr = lane & 15, lg = lane >> 4;

    #pragma unroll
    for (int ss = 0; ss < 8; ++ss) {   // stage W2 slice [128][128]
        int idx = ss*256 + t;
        int row = idx >> 4;
        int c8  = (idx & 15) * 8;
        u16x8 v = *(const u16x8*)(W2 + (size_t)b*32768 + (size_t)(o0+row)*128 + c8);
        *(u16x8*)&As[sw128(row, c8)] = v;
    }
    {   // stage T tile [128 k][128 n] -> Bs[n][k] transposed pair-packed
        int nn_  = t & 127;
        int half = t >> 7;
        const unsigned short* Tb = T + (size_t)b*COUT*NN + n0 + nn_;
        #pragma unroll
        for (int kk = 0; kk < 32; ++kk) {
            int p = kk*2 + half;       // 0..63
            unsigned int lo = Tb[(size_t)(2*p)*NN];
            unsigned int hi = Tb[(size_t)(2*p+1)*NN];
            *(unsigned int*)&Bs[sw128(nn_, p*2)] = lo | (hi << 16);
        }
    }
    __syncthreads();

    f32x4 acc[4][4];
    #pragma unroll
    for (int i=0;i<4;i++)
        #pragma unroll
        for (int j=0;j<4;j++) acc[i][j] = (f32x4){0.f,0.f,0.f,0.f};

    #pragma unroll
    for (int kk = 0; kk < 4; ++kk) {
        bf16x8 af[4], bfr[4];
        #pragma unroll
        for (int mi=0; mi<4; ++mi) {
            int row = wr*64 + mi*16 + lr;
            af[mi] = __builtin_bit_cast(bf16x8, *(const u16x8*)&As[sw128(row, kk*32 + lg*8)]);
        }
        #pragma unroll
        for (int ni=0; ni<4; ++ni) {
            int row = wc*64 + ni*16 + lr;
            bfr[ni] = __builtin_bit_cast(bf16x8, *(const u16x8*)&Bs[sw128(row, kk*32 + lg*8)]);
        }
        #pragma unroll
        for (int mi=0; mi<4; ++mi)
            #pragma unroll
            for (int ni=0; ni<4; ++ni)
                acc[mi][ni] = MFMA(af[mi], bfr[ni], acc[mi][ni]);
    }

    float* ob = out + (size_t)b*CIN*NN;
    #pragma unroll
    for (int mi=0; mi<4; ++mi)
        #pragma unroll
        for (int j=0; j<4; ++j) {
            int o = o0 + wr*64 + mi*16 + lg*4 + j;
            float bv = Wb[o];
            #pragma unroll
            for (int ni=0; ni<4; ++ni) {
                int n = n0 + wc*64 + ni*16 + lr;
                ob[(size_t)o*NN + n] = acc[mi][ni][j] + bv;
            }
        }
}

// ---------------- K5: BN partial sums per channel ----
__global__ __launch_bounds__(256) void k5_stats(const float* __restrict__ wy,
                                                float* __restrict__ stats)
{
    int b = blockIdx.x >> 8, c = blockIdx.x & 255;
    const float4* p = (const float4*)(wy + (size_t)b*CIN*NN + (size_t)c*NN);
    float s1 = 0.f, s2 = 0.f;
    for (int i = threadIdx.x; i < 1024; i += 256) {
        float4 v = p[i];
        s1 += v.x + v.y + v.z + v.w;
        s2 += v.x*v.x + v.y*v.y + v.z*v.z + v.w*v.w;
    }
    for (int off = 32; off > 0; off >>= 1) {
        s1 += __shfl_down(s1, off);
        s2 += __shfl_down(s2, off);
    }
    __shared__ float r1[4], r2[4];
    int w = threadIdx.x >> 6;
    if ((threadIdx.x & 63) == 0) { r1[w] = s1; r2[w] = s2; }
    __syncthreads();
    if (threadIdx.x == 0) {
        s1 = r1[0]+r1[1]+r1[2]+r1[3];
        s2 = r2[0]+r2[1]+r2[2]+r2[3];
        atomicAdd(&stats[c], s1);
        atomicAdd(&stats[256 + c], s2);
    }
}

// ---------------- K6: out = gamma*(wy-mean)*rsqrt(var+eps)+beta + x ----
__global__ __launch_bounds__(256) void k6_final(
    float* __restrict__ out, const float* __restrict__ x,
    const float* __restrict__ stats, const float* __restrict__ gamma,
    const float* __restrict__ beta)
{
    const float inv = 1.0f / (float)(BB * NN);
    int stride = gridDim.x * blockDim.x;
    for (int i = blockIdx.x * blockDim.x + threadIdx.x; i < (BB*CIN*NN)/4; i += stride) {
        int c = (i >> 10) & 255;
        float mean = stats[c] * inv;
        float var  = stats[256 + c] * inv - mean*mean;
        float sc   = gamma[c] * rsqrtf(var + 1e-5f);
        float bb   = beta[c];
        float4 w  = ((const float4*)out)[i];
        float4 xv = ((const float4*)x)[i];
        float4 r;
        r.x = (w.x - mean)*sc + bb + xv.x;
        r.y = (w.y - mean)*sc + bb + xv.y;
        r.z = (w.z - mean)*sc + bb + xv.z;
        r.w = (w.w - mean)*sc + bb + xv.w;
        ((float4*)out)[i] = r;
    }
}

extern "C" void kernel_launch(void* const* d_in, const int* in_sizes, int n_in,
                              void* d_out, int out_size, void* d_ws, size_t ws_size,
                              hipStream_t stream)
{
    (void)in_sizes; (void)n_in; (void)out_size; (void)ws_size;
    const float* x     = (const float*)d_in[0];
    const float* gw    = (const float*)d_in[1];
    const float* gb    = (const float*)d_in[2];
    const float* tw    = (const float*)d_in[3];
    const float* tb    = (const float*)d_in[4];
    const float* pw    = (const float*)d_in[5];
    const float* pb    = (const float*)d_in[6];
    const float* Ww    = (const float*)d_in[7];
    const float* Wb    = (const float*)d_in[8];
    const float* gamma = (const float*)d_in[9];
    const float* beta  = (const float*)d_in[10];
    float* out = (float*)d_out;

    char* ws = (char*)d_ws;
    unsigned short* T  = (unsigned short*)(ws + 0);          //  8.39 MB
    unsigned short* P  = (unsigned short*)(ws + 8388608);    //  8.39 MB
    unsigned short* G  = (unsigned short*)(ws + 16777216);   //  8.39 MB
    float* M1          = (float*)(ws + 25165824);            //  512 KB
    float* stats       = (float*)(ws + 25690112);            //  2 KB
    unsigned short* W2 = (unsigned short*)(ws + 25692160);   //  512 KB

    hipMemsetAsync(ws + 25165824, 0, 524288 + 2048, stream); // zero M1 + stats

    k1_conv3 <<<768,  256, 0, stream>>>(x, gw, gb, tw, tb, pw, pb, G, T, P);
    k2_m1    <<<128,  256, 0, stream>>>(P, G, M1);
    k3_w2    <<<32,   256, 0, stream>>>(Ww, M1, W2);
    k4_wy    <<<512,  256, 0, stream>>>(W2, T, Wb, out);
    k5_stats <<<2048, 256, 0, stream>>>(out, stats);
    k6_final <<<2048, 256, 0, stream>>>(out, x, stats, gamma, beta);
}

// Round 2
// 98.902 us; speedup vs baseline: 1.0201x; 1.0201x over previous
//
#include <hip/hip_runtime.h>
#include <hip/hip_bf16.h>
#include <stdint.h>

#define BB   8
#define CIN  256
#define COUT 128
#define NN   4096

using f32x4  = __attribute__((ext_vector_type(4))) float;
using bf16x8 = __attribute__((ext_vector_type(8))) __bf16;
using u16x8  = __attribute__((ext_vector_type(8))) unsigned short;

static __device__ __forceinline__ unsigned short f2bf(float f) {
    unsigned int u = __builtin_bit_cast(unsigned int, f);
    u += 0x7FFFu + ((u >> 16) & 1u);
    return (unsigned short)(u >> 16);
}
static __device__ __forceinline__ float bf2f(unsigned short u) {
    return __builtin_bit_cast(float, (unsigned int)u << 16);
}
static __device__ __forceinline__ ushort4 pack4(float a, float b, float c, float d) {
    ushort4 r; r.x=f2bf(a); r.y=f2bf(b); r.z=f2bf(c); r.w=f2bf(d); return r;
}
static __device__ __forceinline__ bf16x8 pack8(float4 a, float4 b) {
    u16x8 r;
    r[0]=f2bf(a.x); r[1]=f2bf(a.y); r[2]=f2bf(a.z); r[3]=f2bf(a.w);
    r[4]=f2bf(b.x); r[5]=f2bf(b.y); r[6]=f2bf(b.z); r[7]=f2bf(b.w);
    return __builtin_bit_cast(bf16x8, r);
}
#define MFMA(a,b,c) __builtin_amdgcn_mfma_f32_16x16x32_bf16((a),(b),(c),0,0,0)

// swizzled LDS index (ushort units) for [r][64] tiles
static __device__ __forceinline__ int sw64(int r, int c)  { return (r*64  + c) ^ ((r&7)<<3); }

typedef __attribute__((address_space(3))) unsigned int lds_uint;
typedef __attribute__((address_space(1))) const unsigned int glob_uint;
static __device__ __forceinline__ void glds16(const void* g, void* l) {
    __builtin_amdgcn_global_load_lds((glob_uint*)g, (lds_uint*)l, 16, 0, 0);
}

// ---------------- z0: zero M1+stats, pack Wcat bf16 [384][256] = [g;phi;theta], biascat ----
__global__ __launch_bounds__(256) void z0_prep(
    const float* __restrict__ gw, const float* __restrict__ pw, const float* __restrict__ tw,
    const float* __restrict__ gb, const float* __restrict__ pb, const float* __restrict__ tb,
    float* __restrict__ M1, float* __restrict__ stats,
    unsigned short* __restrict__ Wcat, float* __restrict__ biascat)
{
    int t = blockIdx.x * 256 + threadIdx.x;
    int gs = gridDim.x * 256;
    float4 z = {0.f,0.f,0.f,0.f};
    for (int i = t; i < 32768 + 128; i += gs) {
        if (i < 32768) ((float4*)M1)[i] = z;
        else ((float4*)stats)[i - 32768] = z;
    }
    for (int i = t; i < 24576; i += gs) {
        int flat = i * 4;
        int o = flat >> 8, c = flat & 255;
        const float* src = (o < 128) ? (gw + o*256) : (o < 256) ? (pw + (o-128)*256) : (tw + (o-256)*256);
        float4 f = *(const float4*)(src + c);
        ushort4 u; u.x=f2bf(f.x); u.y=f2bf(f.y); u.z=f2bf(f.z); u.w=f2bf(f.w);
        *(ushort4*)(Wcat + flat) = u;
    }
    if (t < 384)
        biascat[t] = (t < 128) ? gb[t] : (t < 256) ? pb[t-128] : tb[t-256];
}

// ---------------- K1: fused conv1x1 x3. x read ONCE per tile. ----
// Xs[n][c] swizzled; g/phi: mfma(x,W) -> D[n][o] -> store [c][n]; theta: mfma(W,x) -> D[o][n] -> store TT[n][c]
__global__ __launch_bounds__(512) void k1_conv3(
    const float* __restrict__ x, const unsigned short* __restrict__ Wcat,
    const float* __restrict__ biascat,
    unsigned short* __restrict__ G, unsigned short* __restrict__ P,
    unsigned short* __restrict__ TT)
{
    __shared__ __align__(16) unsigned short Xs[128*256];   // 64 KB, chunk-XOR swizzled
    int b  = blockIdx.x >> 5;
    int n0 = (blockIdx.x & 31) * 128;
    int t  = threadIdx.x;

    { // transpose-stage: x[c][n-tile] fp32 -> Xs[n][c] bf16
        int c  = t & 255;
        int nq = (t >> 8) * 64;
        const float* xp = x + ((size_t)b*CIN + c)*NN + n0 + nq;
        #pragma unroll
        for (int r = 0; r < 16; ++r) {
            float4 f = *(const float4*)(xp + r*4);
            int n = nq + r*4;
            Xs[(n+0)*256 + (c ^ (((n+0)&7)<<3))] = f2bf(f.x);
            Xs[(n+1)*256 + (c ^ (((n+1)&7)<<3))] = f2bf(f.y);
            Xs[(n+2)*256 + (c ^ (((n+2)&7)<<3))] = f2bf(f.z);
            Xs[(n+3)*256 + (c ^ (((n+3)&7)<<3))] = f2bf(f.w);
        }
    }
    __syncthreads();

    int lane = t & 63, wv = t >> 6;
    int wr = wv >> 2, wc = wv & 3;        // wave grid 2n x 4o
    int lr = lane & 15, lg = lane >> 4;
    int nb = wr*64, ob = wc*96;

    f32x4 acc[4][6];
    #pragma unroll
    for (int i=0;i<4;i++)
        #pragma unroll
        for (int j=0;j<6;j++) acc[i][j] = (f32x4){0.f,0.f,0.f,0.f};

    #pragma unroll
    for (int ks = 0; ks < 8; ++ks) {
        bf16x8 xf[4], wf[6];
        #pragma unroll
        for (int ni = 0; ni < 4; ++ni) {
            int n = nb + ni*16 + lr;
            int cq = (ks*4 + lg) ^ (n & 7);
            xf[ni] = __builtin_bit_cast(bf16x8, *(const u16x8*)&Xs[n*256 + cq*8]);
        }
        #pragma unroll
        for (int os = 0; os < 6; ++os) {
            int o = ob + os*16 + lr;
            wf[os] = __builtin_bit_cast(bf16x8, *(const u16x8*)(Wcat + (size_t)o*256 + ks*32 + lg*8));
        }
        #pragma unroll
        for (int os = 0; os < 6; ++os) {
            bool th = (ob + os*16) >= 256;
            #pragma unroll
            for (int ni = 0; ni < 4; ++ni)
                acc[ni][os] = th ? MFMA(wf[os], xf[ni], acc[ni][os])
                                 : MFMA(xf[ni], wf[os], acc[ni][os]);
        }
    }

    unsigned short* Gb  = G  + (size_t)b*COUT*NN;
    unsigned short* Pb  = P  + (size_t)b*COUT*NN;
    unsigned short* TTb = TT + (size_t)b*NN*COUT;
    #pragma unroll
    for (int os = 0; os < 6; ++os) {
        int o = ob + os*16;
        if (o < 256) {           // g or phi: lane col o+lr fixed, rows n = nb+ni*16+lg*4+j
            float bv = biascat[o + lr];
            unsigned short* dst = ((o < 128) ? (Gb + (size_t)(o + lr)*NN)
                                             : (Pb + (size_t)(o - 128 + lr)*NN)) + n0 + nb;
            #pragma unroll
            for (int ni = 0; ni < 4; ++ni) {
                f32x4 v = acc[ni][os];
                *(ushort4*)(dst + ni*16 + lg*4) = pack4(v[0]+bv, v[1]+bv, v[2]+bv, v[3]+bv);
            }
        } else {                 // theta: lane col n fixed, rows o = o+lg*4+j -> TT[n][c]
            int c0 = o - 256 + lg*4;
            float b0 = biascat[o + lg*4 + 0];
            float b1 = biascat[o + lg*4 + 1];
            float b2 = biascat[o + lg*4 + 2];
            float b3 = biascat[o + lg*4 + 3];
            #pragma unroll
            for (int ni = 0; ni < 4; ++ni) {
                int n = n0 + nb + ni*16 + lr;
                f32x4 v = acc[ni][os];
                *(ushort4*)(TTb + (size_t)n*COUT + c0) = pack4(v[0]+b0, v[1]+b1, v[2]+b2, v[3]+b3);
            }
        }
    }
}

// ---------------- K2: M1[k][c] += sum_n P[k][n]*G[c][n]  (n-split + atomics) ----
__global__ __launch_bounds__(256) void k2_m1(
    const unsigned short* __restrict__ P, const unsigned short* __restrict__ G,
    float* __restrict__ M1)
{
    __shared__ __align__(16) unsigned short Ps[128*64];
    __shared__ __align__(16) unsigned short Gs[128*64];
    int b  = blockIdx.x >> 4;
    int ks = blockIdx.x & 15;
    int t = threadIdx.x;
    int lane = t & 63, wv = t >> 6;
    int wr = wv >> 1, wc = wv & 1;
    int lr = lane & 15, lg = lane >> 4;

    f32x4 acc[4][4];
    #pragma unroll
    for (int i=0;i<4;i++)
        #pragma unroll
        for (int j=0;j<4;j++) acc[i][j] = (f32x4){0.f,0.f,0.f,0.f};

    const unsigned short* Pb = P + (size_t)b*COUT*NN;
    const unsigned short* Gb = G + (size_t)b*COUT*NN;

    for (int it = 0; it < 4; ++it) {
        int n0 = ks*256 + it*64;
        #pragma unroll
        for (int ss = 0; ss < 4; ++ss) {
            int idx = ss*256 + t;
            int row = idx >> 3;
            int c8  = (idx & 7) * 8;
            u16x8 v = *(const u16x8*)(Pb + (size_t)row*NN + n0 + c8);
            *(u16x8*)&Ps[sw64(row, c8)] = v;
            u16x8 g = *(const u16x8*)(Gb + (size_t)row*NN + n0 + c8);
            *(u16x8*)&Gs[sw64(row, c8)] = g;
        }
        __syncthreads();
        #pragma unroll
        for (int kk = 0; kk < 2; ++kk) {
            bf16x8 af[4], bfr[4];
            #pragma unroll
            for (int mi=0; mi<4; ++mi) {
                int row = wr*64 + mi*16 + lr;
                af[mi] = __builtin_bit_cast(bf16x8, *(const u16x8*)&Ps[sw64(row, kk*32 + lg*8)]);
            }
            #pragma unroll
            for (int ni=0; ni<4; ++ni) {
                int row = wc*64 + ni*16 + lr;
                bfr[ni] = __builtin_bit_cast(bf16x8, *(const u16x8*)&Gs[sw64(row, kk*32 + lg*8)]);
            }
            #pragma unroll
            for (int mi=0; mi<4; ++mi)
                #pragma unroll
                for (int ni=0; ni<4; ++ni)
                    acc[mi][ni] = MFMA(af[mi], bfr[ni], acc[mi][ni]);
        }
        __syncthreads();
    }
    float* m1b = M1 + (size_t)b*16384;
    #pragma unroll
    for (int mi=0; mi<4; ++mi)
        #pragma unroll
        for (int j=0; j<4; ++j) {
            int kch = wr*64 + mi*16 + lg*4 + j;
            #pragma unroll
            for (int ni=0; ni<4; ++ni) {
                int cch = wc*64 + ni*16 + lr;
                atomicAdd(&m1b[kch*128 + cch], acc[mi][ni][j]);
            }
        }
}

// ---------------- K3: W2[b][o][k] = (1/N) * sum_c Ww[o][c] * M1[k][c] -> bf16 ----
__global__ __launch_bounds__(256) void k3_w2(
    const float* __restrict__ Ww, const float* __restrict__ M1,
    unsigned short* __restrict__ W2)
{
    int b = blockIdx.x >> 2, q = blockIdx.x & 3;
    int wv = threadIdx.x >> 6, lane = threadIdx.x & 63;
    int lr = lane & 15, lg = lane >> 4;
    int o16 = q*64 + wv*16;

    bf16x8 a[4];
    const float* wrow = Ww + (size_t)(o16 + lr)*128;
    #pragma unroll
    for (int ksx=0; ksx<4; ++ksx) {
        float4 f0 = *(const float4*)(wrow + ksx*32 + lg*8);
        float4 f1 = *(const float4*)(wrow + ksx*32 + lg*8 + 4);
        a[ksx] = pack8(f0, f1);
    }
    const float* m1b = M1 + (size_t)b*16384;
    for (int kt = 0; kt < 8; ++kt) {
        f32x4 acc = (f32x4){0.f,0.f,0.f,0.f};
        const float* mrow = m1b + (size_t)(kt*16 + lr)*128;
        #pragma unroll
        for (int ksx=0; ksx<4; ++ksx) {
            float4 f0 = *(const float4*)(mrow + ksx*32 + lg*8);
            float4 f1 = *(const float4*)(mrow + ksx*32 + lg*8 + 4);
            bf16x8 bb = pack8(f0, f1);
            acc = MFMA(a[ksx], bb, acc);
        }
        #pragma unroll
        for (int j=0;j<4;++j) {
            int o = o16 + lg*4 + j;
            int k = kt*16 + lr;
            W2[(size_t)b*32768 + (size_t)o*128 + k] = f2bf(acc[j] * (1.0f/4096.0f));
        }
    }
}

// ---------------- K4: wy[b][o][n] = W2[b] @ theta + Wb (bf16 out) + fused BN stats ----
__global__ __launch_bounds__(512) void k4_wy(
    const unsigned short* __restrict__ W2, const unsigned short* __restrict__ TT,
    const float* __restrict__ Wb, unsigned short* __restrict__ WY,
    float* __restrict__ stats)
{
    __shared__ __align__(16) unsigned short Ts[128*128];   // 32 KB, kq-XOR swizzled
    __shared__ float sb[512];
    int b  = blockIdx.x >> 5;
    int n0 = (blockIdx.x & 31) * 128;
    int t  = threadIdx.x;
    int lane = t & 63, wv = t >> 6;
    sb[t] = 0.f;

    // stage TT tile [128n][128k] via global_load_lds, source pre-swizzled
    const unsigned short* TTb = TT + ((size_t)b*NN + n0)*COUT;
    #pragma unroll
    for (int g = 0; g < 4; ++g) {
        int nl = wv*16 + g*4 + (lane >> 4);
        int kq = lane & 15;
        const unsigned short* src = TTb + (size_t)nl*128 + ((kq ^ (nl & 7)) * 8);
        glds16(src, &Ts[(wv*16 + g*4) * 128]);
    }
    asm volatile("s_waitcnt vmcnt(0)");
    __syncthreads();

    int wr = wv >> 2, wo = wv & 3;        // 2n x 4o
    int lr = lane & 15, lg = lane >> 4;
    int nb = wr*64, ob = wo*64;
    const unsigned short* W2b = W2 + (size_t)b*32768;

    f32x4 acc[4][4];
    #pragma unroll
    for (int i=0;i<4;i++)
        #pragma unroll
        for (int j=0;j<4;j++) acc[i][j] = (f32x4){0.f,0.f,0.f,0.f};

    #pragma unroll
    for (int ks = 0; ks < 4; ++ks) {
        bf16x8 tf[4], wf[4];
        #pragma unroll
        for (int ni = 0; ni < 4; ++ni) {
            int n = nb + ni*16 + lr;
            int kq = (ks*4 + lg) ^ (n & 7);
            tf[ni] = __builtin_bit_cast(bf16x8, *(const u16x8*)&Ts[n*128 + kq*8]);
        }
        #pragma unroll
        for (int oi = 0; oi < 4; ++oi) {
            int o = ob + oi*16 + lr;
            wf[oi] = __builtin_bit_cast(bf16x8, *(const u16x8*)(W2b + (size_t)o*128 + ks*32 + lg*8));
        }
        #pragma unroll
        for (int ni = 0; ni < 4; ++ni)
            #pragma unroll
            for (int oi = 0; oi < 4; ++oi)
                acc[ni][oi] = MFMA(tf[ni], wf[oi], acc[ni][oi]);
    }

    // D[n][o]: lane col o = ob+oi*16+lr fixed; rows n = nb+ni*16+lg*4+j
    unsigned short* wyb = WY + (size_t)b*CIN*NN;
    #pragma unroll
    for (int oi = 0; oi < 4; ++oi) {
        int o = ob + oi*16 + lr;
        float bv = Wb[o];
        float s1 = 0.f, s2 = 0.f;
        #pragma unroll
        for (int ni = 0; ni < 4; ++ni) {
            f32x4 v = acc[ni][oi];
            float v0 = v[0]+bv, v1 = v[1]+bv, v2 = v[2]+bv, v3 = v[3]+bv;
            s1 += v0+v1+v2+v3;
            s2 += v0*v0+v1*v1+v2*v2+v3*v3;
            *(ushort4*)(wyb + (size_t)o*NN + n0 + nb + ni*16 + lg*4) = pack4(v0,v1,v2,v3);
        }
        s1 += __shfl_xor(s1, 16); s1 += __shfl_xor(s1, 32);
        s2 += __shfl_xor(s2, 16); s2 += __shfl_xor(s2, 32);
        if (lg == 0) {
            atomicAdd(&sb[o], s1);
            atomicAdd(&sb[256 + o], s2);
        }
    }
    __syncthreads();
    atomicAdd(&stats[t], sb[t]);
}

// ---------------- K6: out = gamma*(wy-mean)*rsqrt(var+eps)+beta + x ----
__global__ __launch_bounds__(256) void k6_final(
    const unsigned short* __restrict__ WY, const float* __restrict__ x,
    const float* __restrict__ stats, const float* __restrict__ gamma,
    const float* __restrict__ beta, float* __restrict__ out)
{
    const float inv = 1.0f / (float)(BB * NN);
    int stride = gridDim.x * blockDim.x;
    for (int i = blockIdx.x * blockDim.x + threadIdx.x; i < (BB*CIN*NN)/8; i += stride) {
        int c = (i >> 9) & 255;
        float mean = stats[c] * inv;
        float var  = stats[256 + c] * inv - mean*mean;
        float sc   = gamma[c] * rsqrtf(var + 1e-5f);
        float bb   = beta[c];
        u16x8 w = ((const u16x8*)WY)[i];
        float4 x0 = ((const float4*)x)[i*2];
        float4 x1 = ((const float4*)x)[i*2+1];
        float4 r0, r1;
        r0.x = (bf2f(w[0]) - mean)*sc + bb + x0.x;
        r0.y = (bf2f(w[1]) - mean)*sc + bb + x0.y;
        r0.z = (bf2f(w[2]) - mean)*sc + bb + x0.z;
        r0.w = (bf2f(w[3]) - mean)*sc + bb + x0.w;
        r1.x = (bf2f(w[4]) - mean)*sc + bb + x1.x;
        r1.y = (bf2f(w[5]) - mean)*sc + bb + x1.y;
        r1.z = (bf2f(w[6]) - mean)*sc + bb + x1.z;
        r1.w = (bf2f(w[7]) - mean)*sc + bb + x1.w;
        ((float4*)out)[i*2]   = r0;
        ((float4*)out)[i*2+1] = r1;
    }
}

extern "C" void kernel_launch(void* const* d_in, const int* in_sizes, int n_in,
                              void* d_out, int out_size, void* d_ws, size_t ws_size,
                              hipStream_t stream)
{
    (void)in_sizes; (void)n_in; (void)out_size; (void)ws_size;
    const float* x     = (const float*)d_in[0];
    const float* gw    = (const float*)d_in[1];
    const float* gb    = (const float*)d_in[2];
    const float* tw    = (const float*)d_in[3];
    const float* tb    = (const float*)d_in[4];
    const float* pw    = (const float*)d_in[5];
    const float* pb    = (const float*)d_in[6];
    const float* Ww    = (const float*)d_in[7];
    const float* Wb    = (const float*)d_in[8];
    const float* gamma = (const float*)d_in[9];
    const float* beta  = (const float*)d_in[10];
    float* out = (float*)d_out;

    char* ws = (char*)d_ws;
    unsigned short* G    = (unsigned short*)(ws + 0);                 // 8 MB
    unsigned short* P    = (unsigned short*)(ws + (8u<<20));          // 8 MB
    unsigned short* WY   = (unsigned short*)(ws + 0);                 // 16 MB, aliases G+P (dead after k2)
    unsigned short* TT   = (unsigned short*)(ws + (16u<<20));         // 8 MB
    float* M1            = (float*)(ws + (24u<<20));                  // 512 KB
    unsigned short* W2   = (unsigned short*)(ws + (24u<<20) + 524288);// 512 KB
    unsigned short* Wcat = (unsigned short*)(ws + (25u<<20));         // 192 KB
    float* biascat       = (float*)(ws + (25u<<20) + 196608);         // 1.5 KB
    float* stats         = (float*)(ws + (25u<<20) + 198656);         // 2 KB

    z0_prep <<<128,  256, 0, stream>>>(gw, pw, tw, gb, pb, tb, M1, stats, Wcat, biascat);
    k1_conv3<<<256,  512, 0, stream>>>(x, Wcat, biascat, G, P, TT);
    k2_m1   <<<128,  256, 0, stream>>>(P, G, M1);
    k3_w2   <<<32,   256, 0, stream>>>(Ww, M1, W2);
    k4_wy   <<<256,  512, 0, stream>>>(W2, TT, Wb, WY, stats);
    k6_final<<<2048, 256, 0, stream>>>(WY, x, stats, gamma, beta, out);
}

// Round 3
// 96.354 us; speedup vs baseline: 1.0471x; 1.0264x over previous
//
#include <hip/hip_runtime.h>
#include <hip/hip_bf16.h>
#include <stdint.h>

#define BB   8
#define CIN  256
#define COUT 128
#define NN   4096

using f32x4  = __attribute__((ext_vector_type(4))) float;
using bf16x8 = __attribute__((ext_vector_type(8))) __bf16;
using u16x8  = __attribute__((ext_vector_type(8))) unsigned short;

static __device__ __forceinline__ unsigned short f2bf(float f) {
    unsigned int u = __builtin_bit_cast(unsigned int, f);
    u += 0x7FFFu + ((u >> 16) & 1u);
    return (unsigned short)(u >> 16);
}
static __device__ __forceinline__ float bf2f(unsigned short u) {
    return __builtin_bit_cast(float, (unsigned int)u << 16);
}
static __device__ __forceinline__ ushort4 pack4(float a, float b, float c, float d) {
    ushort4 r; r.x=f2bf(a); r.y=f2bf(b); r.z=f2bf(c); r.w=f2bf(d); return r;
}
static __device__ __forceinline__ bf16x8 pack8(float4 a, float4 b) {
    u16x8 r;
    r[0]=f2bf(a.x); r[1]=f2bf(a.y); r[2]=f2bf(a.z); r[3]=f2bf(a.w);
    r[4]=f2bf(b.x); r[5]=f2bf(b.y); r[6]=f2bf(b.z); r[7]=f2bf(b.w);
    return __builtin_bit_cast(bf16x8, r);
}
#define MFMA(a,b,c) __builtin_amdgcn_mfma_f32_16x16x32_bf16((a),(b),(c),0,0,0)

// swizzled LDS index (ushort units) for [r][64] tiles: XOR chunk-of-8 with row&7
static __device__ __forceinline__ int sw64(int r, int c)  { return (r*64  + c) ^ ((r&7)<<3); }

typedef __attribute__((address_space(3))) unsigned int lds_uint;
typedef __attribute__((address_space(1))) const unsigned int glob_uint;
static __device__ __forceinline__ void glds16(const void* g, void* l) {
    __builtin_amdgcn_global_load_lds((glob_uint*)g, (lds_uint*)l, 16, 0, 0);
}

// ---------------- z0: zero stats, pack Wcat bf16 [384][256] = [g;phi;theta], biascat ----
__global__ __launch_bounds__(256) void z0_prep(
    const float* __restrict__ gw, const float* __restrict__ pw, const float* __restrict__ tw,
    const float* __restrict__ gb, const float* __restrict__ pb, const float* __restrict__ tb,
    float* __restrict__ stats,
    unsigned short* __restrict__ Wcat, float* __restrict__ biascat)
{
    int t = blockIdx.x * 256 + threadIdx.x;
    int gs = gridDim.x * 256;
    for (int i = t; i < 24576; i += gs) {
        int flat = i * 4;
        int o = flat >> 8, c = flat & 255;
        const float* src = (o < 128) ? (gw + o*256) : (o < 256) ? (pw + (o-128)*256) : (tw + (o-256)*256);
        float4 f = *(const float4*)(src + c);
        ushort4 u; u.x=f2bf(f.x); u.y=f2bf(f.y); u.z=f2bf(f.z); u.w=f2bf(f.w);
        *(ushort4*)(Wcat + flat) = u;
    }
    if (t < 512) stats[t] = 0.f;
    if (t < 384)
        biascat[t] = (t < 128) ? gb[t] : (t < 256) ? pb[t-128] : tb[t-256];
}

// ---------------- K1: fused conv1x1 x3, coalesced transpose staging ----
__global__ __launch_bounds__(512) void k1_conv3(
    const float* __restrict__ x, const unsigned short* __restrict__ Wcat,
    const float* __restrict__ biascat,
    unsigned short* __restrict__ G, unsigned short* __restrict__ P,
    unsigned short* __restrict__ TT)
{
    __shared__ __align__(16) unsigned short Xs[128*256];   // 64 KB, [n][c] chunk-XOR swizzled
    int b  = blockIdx.x >> 5;
    int n0 = (blockIdx.x & 31) * 128;
    int t  = threadIdx.x;

    { // coalesced transpose-stage: lanes read contiguous n-spans of 4 consecutive c-rows
        int nq = (t & 31) * 4;         // n offset 0..124
        int c0 = (t >> 5) * 4;         // c offset 0..60
        const float* xb = x + (size_t)b*CIN*NN + n0 + nq;
        #pragma unroll
        for (int p = 0; p < 4; ++p) {
            int c = p*64 + c0;
            const float* xp = xb + (size_t)c*NN;
            float4 f0 = *(const float4*)(xp);
            float4 f1 = *(const float4*)(xp + NN);
            float4 f2 = *(const float4*)(xp + 2*NN);
            float4 f3 = *(const float4*)(xp + 3*NN);
            *(ushort4*)&Xs[(nq+0)*256 + (c ^ (((nq+0)&7)<<3))] = pack4(f0.x,f1.x,f2.x,f3.x);
            *(ushort4*)&Xs[(nq+1)*256 + (c ^ (((nq+1)&7)<<3))] = pack4(f0.y,f1.y,f2.y,f3.y);
            *(ushort4*)&Xs[(nq+2)*256 + (c ^ (((nq+2)&7)<<3))] = pack4(f0.z,f1.z,f2.z,f3.z);
            *(ushort4*)&Xs[(nq+3)*256 + (c ^ (((nq+3)&7)<<3))] = pack4(f0.w,f1.w,f2.w,f3.w);
        }
    }
    __syncthreads();

    int lane = t & 63, wv = t >> 6;
    int wr = wv >> 2, wc = wv & 3;        // wave grid 2n x 4o
    int lr = lane & 15, lg = lane >> 4;
    int nb = wr*64, ob = wc*96;

    f32x4 acc[4][6];
    #pragma unroll
    for (int i=0;i<4;i++)
        #pragma unroll
        for (int j=0;j<6;j++) acc[i][j] = (f32x4){0.f,0.f,0.f,0.f};

    #pragma unroll
    for (int ks = 0; ks < 8; ++ks) {
        bf16x8 xf[4], wf[6];
        #pragma unroll
        for (int ni = 0; ni < 4; ++ni) {
            int n = nb + ni*16 + lr;
            int cq = (ks*4 + lg) ^ (n & 7);
            xf[ni] = __builtin_bit_cast(bf16x8, *(const u16x8*)&Xs[n*256 + cq*8]);
        }
        #pragma unroll
        for (int os = 0; os < 6; ++os) {
            int o = ob + os*16 + lr;
            wf[os] = __builtin_bit_cast(bf16x8, *(const u16x8*)(Wcat + (size_t)o*256 + ks*32 + lg*8));
        }
        #pragma unroll
        for (int os = 0; os < 6; ++os) {
            bool th = (ob + os*16) >= 256;
            #pragma unroll
            for (int ni = 0; ni < 4; ++ni)
                acc[ni][os] = th ? MFMA(wf[os], xf[ni], acc[ni][os])
                                 : MFMA(xf[ni], wf[os], acc[ni][os]);
        }
    }

    unsigned short* Gb  = G  + (size_t)b*COUT*NN;
    unsigned short* Pb  = P  + (size_t)b*COUT*NN;
    unsigned short* TTb = TT + (size_t)b*NN*COUT;
    #pragma unroll
    for (int os = 0; os < 6; ++os) {
        int o = ob + os*16;
        if (o < 256) {           // g or phi: D[n][o], lane col o+lr fixed
            float bv = biascat[o + lr];
            unsigned short* dst = ((o < 128) ? (Gb + (size_t)(o + lr)*NN)
                                             : (Pb + (size_t)(o - 128 + lr)*NN)) + n0 + nb;
            #pragma unroll
            for (int ni = 0; ni < 4; ++ni) {
                f32x4 v = acc[ni][os];
                *(ushort4*)(dst + ni*16 + lg*4) = pack4(v[0]+bv, v[1]+bv, v[2]+bv, v[3]+bv);
            }
        } else {                 // theta: D[o][n] -> store TT[n][c]
            int c0 = o - 256 + lg*4;
            float b0 = biascat[o + lg*4 + 0];
            float b1 = biascat[o + lg*4 + 1];
            float b2 = biascat[o + lg*4 + 2];
            float b3 = biascat[o + lg*4 + 3];
            #pragma unroll
            for (int ni = 0; ni < 4; ++ni) {
                int n = n0 + nb + ni*16 + lr;
                f32x4 v = acc[ni][os];
                *(ushort4*)(TTb + (size_t)n*COUT + c0) = pack4(v[0]+b0, v[1]+b1, v[2]+b2, v[3]+b3);
            }
        }
    }
}

// ---------------- K2: M1p[bid][k][c] = sum_{n in chunk} P[k][n]*G[c][n] ----
__global__ __launch_bounds__(256) void k2_m1(
    const unsigned short* __restrict__ P, const unsigned short* __restrict__ G,
    float* __restrict__ M1p)
{
    __shared__ __align__(16) unsigned short Ps[128*64];
    __shared__ __align__(16) unsigned short Gs[128*64];
    int bid = blockIdx.x;
    int b  = bid >> 4;
    int ks = bid & 15;
    int t = threadIdx.x;
    int lane = t & 63, wv = t >> 6;
    int wr = wv >> 1, wc = wv & 1;
    int lr = lane & 15, lg = lane >> 4;

    f32x4 acc[4][4];
    #pragma unroll
    for (int i=0;i<4;i++)
        #pragma unroll
        for (int j=0;j<4;j++) acc[i][j] = (f32x4){0.f,0.f,0.f,0.f};

    const unsigned short* Pb = P + (size_t)b*COUT*NN;
    const unsigned short* Gb = G + (size_t)b*COUT*NN;

    for (int it = 0; it < 4; ++it) {
        int n0 = ks*256 + it*64;
        // stage via global_load_lds: linear dest, inverse-swizzled per-lane source
        #pragma unroll
        for (int g4 = 0; g4 < 4; ++g4) {
            int row0 = wv*32 + g4*8;
            int row  = row0 + (lane >> 3);
            int gg   = (lane & 7) ^ (row & 7);
            glds16(Pb + (size_t)row*NN + n0 + gg*8, &Ps[row0*64]);
            glds16(Gb + (size_t)row*NN + n0 + gg*8, &Gs[row0*64]);
        }
        asm volatile("s_waitcnt vmcnt(0)");
        __syncthreads();
        #pragma unroll
        for (int kk = 0; kk < 2; ++kk) {
            bf16x8 af[4], bfr[4];
            #pragma unroll
            for (int mi=0; mi<4; ++mi) {
                int row = wr*64 + mi*16 + lr;
                af[mi] = __builtin_bit_cast(bf16x8, *(const u16x8*)&Ps[sw64(row, kk*32 + lg*8)]);
            }
            #pragma unroll
            for (int ni=0; ni<4; ++ni) {
                int row = wc*64 + ni*16 + lr;
                bfr[ni] = __builtin_bit_cast(bf16x8, *(const u16x8*)&Gs[sw64(row, kk*32 + lg*8)]);
            }
            #pragma unroll
            for (int mi=0; mi<4; ++mi)
                #pragma unroll
                for (int ni=0; ni<4; ++ni)
                    acc[mi][ni] = MFMA(af[mi], bfr[ni], acc[mi][ni]);
        }
        __syncthreads();
    }
    float* dst = M1p + (size_t)bid*16384;
    #pragma unroll
    for (int mi=0; mi<4; ++mi)
        #pragma unroll
        for (int j=0; j<4; ++j) {
            int kch = wr*64 + mi*16 + lg*4 + j;
            #pragma unroll
            for (int ni=0; ni<4; ++ni) {
                int cch = wc*64 + ni*16 + lr;
                dst[kch*128 + cch] = acc[mi][ni][j];
            }
        }
}

// ---------------- K3: reduce 16 partials -> M1 in LDS; W2[o][k] = (1/N)*Ww@M1^T ----
__global__ __launch_bounds__(512) void k3_w2(
    const float* __restrict__ Ww, const float* __restrict__ M1p,
    unsigned short* __restrict__ W2)
{
    __shared__ float Ms[16384];        // 64 KB, float4-chunk XOR swizzled
    int b = blockIdx.x;
    int t = threadIdx.x;

    for (int i4 = t; i4 < 4096; i4 += 512) {
        float4 s = {0.f,0.f,0.f,0.f};
        #pragma unroll
        for (int p = 0; p < 16; ++p) {
            float4 v = ((const float4*)(M1p + (size_t)(b*16 + p)*16384))[i4];
            s.x += v.x; s.y += v.y; s.z += v.z; s.w += v.w;
        }
        int k = i4 >> 5, q = i4 & 31;
        *(float4*)&Ms[k*128 + ((q ^ (k&7)) * 4)] = s;
    }
    __syncthreads();

    int lane = t & 63, wv = t >> 6;
    int lr = lane & 15, lg = lane >> 4;
    #pragma unroll
    for (int oo = 0; oo < 2; ++oo) {
        int o16 = oo*128 + wv*16;
        bf16x8 a[4];
        const float* wrow = Ww + (size_t)(o16 + lr)*128;
        #pragma unroll
        for (int ksx=0; ksx<4; ++ksx) {
            float4 f0 = *(const float4*)(wrow + ksx*32 + lg*8);
            float4 f1 = *(const float4*)(wrow + ksx*32 + lg*8 + 4);
            a[ksx] = pack8(f0, f1);
        }
        for (int kt = 0; kt < 8; ++kt) {
            f32x4 acc = (f32x4){0.f,0.f,0.f,0.f};
            int k = kt*16 + lr;
            #pragma unroll
            for (int ksx=0; ksx<4; ++ksx) {
                int q0 = ksx*8 + lg*2;
                float4 f0 = *(const float4*)&Ms[k*128 + ((q0     ^ (k&7)) * 4)];
                float4 f1 = *(const float4*)&Ms[k*128 + (((q0+1) ^ (k&7)) * 4)];
                acc = MFMA(a[ksx], pack8(f0, f1), acc);
            }
            #pragma unroll
            for (int j=0;j<4;++j) {
                int o = o16 + lg*4 + j;
                W2[(size_t)b*32768 + (size_t)o*128 + (kt*16 + lr)] = f2bf(acc[j] * (1.0f/4096.0f));
            }
        }
    }
}

// ---------------- K4: wy[b][o][n] = W2[b] @ theta + Wb (bf16 out) + fused BN stats ----
__global__ __launch_bounds__(512) void k4_wy(
    const unsigned short* __restrict__ W2, const unsigned short* __restrict__ TT,
    const float* __restrict__ Wb, unsigned short* __restrict__ WY,
    float* __restrict__ stats)
{
    __shared__ __align__(16) unsigned short Ts[128*128];   // 32 KB, kq-XOR swizzled
    __shared__ float sb[512];
    int b  = blockIdx.x >> 5;
    int n0 = (blockIdx.x & 31) * 128;
    int t  = threadIdx.x;
    int lane = t & 63, wv = t >> 6;
    sb[t] = 0.f;

    const unsigned short* TTb = TT + ((size_t)b*NN + n0)*COUT;
    #pragma unroll
    for (int g = 0; g < 4; ++g) {
        int nl = wv*16 + g*4 + (lane >> 4);
        int kq = lane & 15;
        const unsigned short* src = TTb + (size_t)nl*128 + ((kq ^ (nl & 7)) * 8);
        glds16(src, &Ts[(wv*16 + g*4) * 128]);
    }
    asm volatile("s_waitcnt vmcnt(0)");
    __syncthreads();

    int wr = wv >> 2, wo = wv & 3;        // 2n x 4o
    int lr = lane & 15, lg = lane >> 4;
    int nb = wr*64, ob = wo*64;
    const unsigned short* W2b = W2 + (size_t)b*32768;

    f32x4 acc[4][4];
    #pragma unroll
    for (int i=0;i<4;i++)
        #pragma unroll
        for (int j=0;j<4;j++) acc[i][j] = (f32x4){0.f,0.f,0.f,0.f};

    #pragma unroll
    for (int ks = 0; ks < 4; ++ks) {
        bf16x8 tf[4], wf[4];
        #pragma unroll
        for (int ni = 0; ni < 4; ++ni) {
            int n = nb + ni*16 + lr;
            int kq = (ks*4 + lg) ^ (n & 7);
            tf[ni] = __builtin_bit_cast(bf16x8, *(const u16x8*)&Ts[n*128 + kq*8]);
        }
        #pragma unroll
        for (int oi = 0; oi < 4; ++oi) {
            int o = ob + oi*16 + lr;
            wf[oi] = __builtin_bit_cast(bf16x8, *(const u16x8*)(W2b + (size_t)o*128 + ks*32 + lg*8));
        }
        #pragma unroll
        for (int ni = 0; ni < 4; ++ni)
            #pragma unroll
            for (int oi = 0; oi < 4; ++oi)
                acc[ni][oi] = MFMA(tf[ni], wf[oi], acc[ni][oi]);
    }

    unsigned short* wyb = WY + (size_t)b*CIN*NN;
    #pragma unroll
    for (int oi = 0; oi < 4; ++oi) {
        int o = ob + oi*16 + lr;
        float bv = Wb[o];
        float s1 = 0.f, s2 = 0.f;
        #pragma unroll
        for (int ni = 0; ni < 4; ++ni) {
            f32x4 v = acc[ni][oi];
            float v0 = v[0]+bv, v1 = v[1]+bv, v2 = v[2]+bv, v3 = v[3]+bv;
            s1 += v0+v1+v2+v3;
            s2 += v0*v0+v1*v1+v2*v2+v3*v3;
            *(ushort4*)(wyb + (size_t)o*NN + n0 + nb + ni*16 + lg*4) = pack4(v0,v1,v2,v3);
        }
        s1 += __shfl_xor(s1, 16); s1 += __shfl_xor(s1, 32);
        s2 += __shfl_xor(s2, 16); s2 += __shfl_xor(s2, 32);
        if (lg == 0) {
            atomicAdd(&sb[o], s1);
            atomicAdd(&sb[256 + o], s2);
        }
    }
    __syncthreads();
    atomicAdd(&stats[t], sb[t]);
}

// ---------------- K6: out = gamma*(wy-mean)*rsqrt(var+eps)+beta + x ----
__global__ __launch_bounds__(256) void k6_final(
    const unsigned short* __restrict__ WY, const float* __restrict__ x,
    const float* __restrict__ stats, const float* __restrict__ gamma,
    const float* __restrict__ beta, float* __restrict__ out)
{
    const float inv = 1.0f / (float)(BB * NN);
    int stride = gridDim.x * blockDim.x;
    for (int i = blockIdx.x * blockDim.x + threadIdx.x; i < (BB*CIN*NN)/8; i += stride) {
        int c = (i >> 9) & 255;
        float mean = stats[c] * inv;
        float var  = stats[256 + c] * inv - mean*mean;
        float sc   = gamma[c] * rsqrtf(var + 1e-5f);
        float bb   = beta[c];
        u16x8 w = ((const u16x8*)WY)[i];
        float4 x0 = ((const float4*)x)[i*2];
        float4 x1 = ((const float4*)x)[i*2+1];
        float4 r0, r1;
        r0.x = (bf2f(w[0]) - mean)*sc + bb + x0.x;
        r0.y = (bf2f(w[1]) - mean)*sc + bb + x0.y;
        r0.z = (bf2f(w[2]) - mean)*sc + bb + x0.z;
        r0.w = (bf2f(w[3]) - mean)*sc + bb + x0.w;
        r1.x = (bf2f(w[4]) - mean)*sc + bb + x1.x;
        r1.y = (bf2f(w[5]) - mean)*sc + bb + x1.y;
        r1.z = (bf2f(w[6]) - mean)*sc + bb + x1.z;
        r1.w = (bf2f(w[7]) - mean)*sc + bb + x1.w;
        ((float4*)out)[i*2]   = r0;
        ((float4*)out)[i*2+1] = r1;
    }
}

extern "C" void kernel_launch(void* const* d_in, const int* in_sizes, int n_in,
                              void* d_out, int out_size, void* d_ws, size_t ws_size,
                              hipStream_t stream)
{
    (void)in_sizes; (void)n_in; (void)out_size; (void)ws_size;
    const float* x     = (const float*)d_in[0];
    const float* gw    = (const float*)d_in[1];
    const float* gb    = (const float*)d_in[2];
    const float* tw    = (const float*)d_in[3];
    const float* tb    = (const float*)d_in[4];
    const float* pw    = (const float*)d_in[5];
    const float* pb    = (const float*)d_in[6];
    const float* Ww    = (const float*)d_in[7];
    const float* Wb    = (const float*)d_in[8];
    const float* gamma = (const float*)d_in[9];
    const float* beta  = (const float*)d_in[10];
    float* out = (float*)d_out;

    char* ws = (char*)d_ws;
    unsigned short* G    = (unsigned short*)(ws + 0);            // 8 MB
    unsigned short* P    = (unsigned short*)(ws + (8u<<20));     // 8 MB
    unsigned short* WY   = (unsigned short*)(ws + 0);            // 16 MB, aliases G+P (dead after k2)
    unsigned short* TT   = (unsigned short*)(ws + (16u<<20));    // 8 MB
    float* M1p           = (float*)(ws + (24u<<20));             // 8 MB (128 partials x 64KB)
    unsigned short* W2   = (unsigned short*)(ws + (32u<<20));    // 512 KB
    unsigned short* Wcat = (unsigned short*)(ws + (33u<<20));    // 192 KB
    float* biascat       = (float*)(ws + (33u<<20) + 196608);    // 1.5 KB
    float* stats         = (float*)(ws + (33u<<20) + 198656);    // 2 KB

    z0_prep <<<96,   256, 0, stream>>>(gw, pw, tw, gb, pb, tb, stats, Wcat, biascat);
    k1_conv3<<<256,  512, 0, stream>>>(x, Wcat, biascat, G, P, TT);
    k2_m1   <<<128,  256, 0, stream>>>(P, G, M1p);
    k3_w2   <<<8,    512, 0, stream>>>(Ww, M1p, W2);
    k4_wy   <<<256,  512, 0, stream>>>(W2, TT, Wb, WY, stats);
    k6_final<<<2048, 256, 0, stream>>>(WY, x, stats, gamma, beta, out);
}